// Round 9
// baseline (396.315 us; speedup 1.0000x reference)
//
#include <hip/hip_runtime.h>
#include <hip/hip_fp16.h>

#define THREADS 256
#define BIN_C 4096           // edges per block chunk (16/thread, held in registers)
#define NBMAX 400            // LDS histogram size (>= bucket count 391)
#define CAP 4608             // bucket capacity (mean 4090, sd ~64 -> 8 sigma slack)
#define SH_U 8               // 256 user nodes / bucket
#define SH_I 7               // 128 item nodes / bucket
#define CPAD 16              // one 64B line per bucket counter
#define T_TILES 8            // neighbor tiles per direction (adjacency tile-sort)
#define TSH_U 13             // item id >> 13 -> tile (50000/8192 = 6.1 < 8)
#define TSH_I 14             // user id >> 14 -> tile (100000/16384 = 6.1 < 8)
#define KNODES 4             // nodes per 8-lane group in tile-phased prop

// ---------------- bin: block-aggregated bucket scatter ----------------
__global__ void bin_kernel(const int* __restrict__ eu, const int* __restrict__ ei,
                           int* __restrict__ bcnt_u, int* __restrict__ bcnt_i,
                           int* __restrict__ binu, int* __restrict__ bini,
                           int E, int nbu, int nbi) {
    __shared__ int hist_u[NBMAX], hist_i[NBMAX];
    __shared__ int base_u[NBMAX], base_i[NBMAX];
    int tid = threadIdx.x;
    int e0 = blockIdx.x * BIN_C;
    if (e0 >= E) return;
    int cnt = min(BIN_C, E - e0);

    for (int b = tid; b < NBMAX; b += THREADS) { hist_u[b] = 0; hist_i[b] = 0; }
    __syncthreads();

    int u[16], v[16];
    #pragma unroll
    for (int j = 0; j < 16; ++j) {
        int k = tid + j * THREADS;
        if (k < cnt) { u[j] = eu[e0 + k]; v[j] = ei[e0 + k]; }
        else         { u[j] = -1; v[j] = -1; }
    }
    #pragma unroll
    for (int j = 0; j < 16; ++j) {
        if (u[j] >= 0) {
            atomicAdd(&hist_u[u[j] >> SH_U], 1);
            atomicAdd(&hist_i[v[j] >> SH_I], 1);
        }
    }
    __syncthreads();
    for (int b = tid; b < NBMAX; b += THREADS) {
        int cu = hist_u[b], ci = hist_i[b];
        base_u[b] = (cu > 0 && b < nbu) ? atomicAdd(&bcnt_u[(size_t)b * CPAD], cu) : 0;
        base_i[b] = (ci > 0 && b < nbi) ? atomicAdd(&bcnt_i[(size_t)b * CPAD], ci) : 0;
        hist_u[b] = 0; hist_i[b] = 0;      // reuse as intra-block cursors
    }
    __syncthreads();
    #pragma unroll
    for (int j = 0; j < 16; ++j) {
        if (u[j] >= 0) {
            int bu = u[j] >> SH_U;
            int pu = base_u[bu] + atomicAdd(&hist_u[bu], 1);
            if (pu < CAP) binu[(size_t)bu * CAP + pu] = ((u[j] & 255) << 16) | v[j];  // i < 2^16
            int bi = v[j] >> SH_I;
            int pi = base_i[bi] + atomicAdd(&hist_i[bi], 1);
            if (pi < CAP) bini[(size_t)bi * CAP + pi] = ((v[j] & 127) << 17) | u[j];  // u < 2^17
        }
    }
}

// ---------------- bucket region assignment (order-free wave scan) ----------------
__global__ void bucket_off(const int* __restrict__ bcnt, int* __restrict__ bo,
                           int* __restrict__ cursor, int nb, int pad) {
    int idx = blockIdx.x * blockDim.x + threadIdx.x;
    int lane = threadIdx.x & 63;
    int d = 0;
    if (idx < nb) d = min(bcnt[(size_t)idx * CPAD], CAP) + pad;
    int s = d;
    #pragma unroll
    for (int ofs = 1; ofs < 64; ofs <<= 1) {
        int t = __shfl_up(s, ofs);
        if (lane >= ofs) s += t;
    }
    int total = __shfl(s, 63);
    int base = 0;
    if (lane == 63) base = atomicAdd(cursor, total);
    base = __shfl(base, 63);
    if (idx < nb) bo[idx] = base + s - d;
}

// ---------------- place: counting sort by (node, nbr_tile) -> tile-sorted CSR ----------------
// Also emits tileoff[node*8+t] = absolute start of node's tile-t segment, so
// the tile-phased prop kernel can sweep tiles in lockstep.
__global__ void place(const int* __restrict__ bcnt_u, const int* __restrict__ bcnt_i,
                      const int* __restrict__ bo_u, const int* __restrict__ bo_i,
                      const int* __restrict__ binu, const int* __restrict__ bini,
                      int* __restrict__ offu, int* __restrict__ offi,
                      int* __restrict__ du, int* __restrict__ di,
                      float* __restrict__ rsdu, float* __restrict__ rsdi,
                      int* __restrict__ entu, int* __restrict__ enti,
                      int* __restrict__ tofu, int* __restrict__ tofi,
                      int nbu, int nU, int nI) {
    __shared__ int stash[CAP];
    __shared__ int bin_cnt[THREADS * T_TILES];   // 2048 bins (cnt -> prefix -> cursor)
    __shared__ int scan[THREADS];
    __shared__ int node_base[THREADS];
    int b = blockIdx.x;
    bool isU = (b < nbu);
    const int* bin; int base_node, nn, count, bob;
    int *off, *deg, *ent, *tof; float* rsd;
    int losh, tsh, lomask;
    if (isU) {
        bin = binu + (size_t)b * CAP;
        base_node = b << SH_U; nn = min(256, nU - base_node);
        count = min(bcnt_u[(size_t)b * CPAD], CAP); bob = bo_u[b];
        off = offu; deg = du; rsd = rsdu; ent = entu; tof = tofu;
        losh = 16; tsh = TSH_U; lomask = 0xFFFF;
    } else {
        int b2 = b - nbu;
        bin = bini + (size_t)b2 * CAP;
        base_node = b2 << SH_I; nn = min(128, nI - base_node);
        count = min(bcnt_i[(size_t)b2 * CPAD], CAP); bob = bo_i[b2];
        off = offi; deg = di; rsd = rsdi; ent = enti; tof = tofi;
        losh = 17; tsh = TSH_I; lomask = 0x1FFFF;
    }
    int tid = threadIdx.x;
    #pragma unroll
    for (int t = 0; t < T_TILES; ++t) bin_cnt[tid + t * THREADS] = 0;  // strided zero
    __syncthreads();
    for (int k = tid; k < count; k += THREADS) {
        int p = bin[k];
        stash[k] = p;
        int key = ((p >> losh) << 3) | ((p & lomask) >> tsh);
        atomicAdd(&bin_cnt[key], 1);
    }
    __syncthreads();
    // intra-node exclusive prefix over the node's 8 tile-bins; c = node degree
    int c = 0;
    {
        int base = tid * T_TILES;
        #pragma unroll
        for (int t = 0; t < T_TILES; ++t) {
            int v = bin_cnt[base + t];
            bin_cnt[base + t] = c;
            c += v;
        }
    }
    int seg = (c + 15) & ~15;               // 64B-align per-node segment
    scan[tid] = seg;
    __syncthreads();
    #pragma unroll
    for (int ofs = 1; ofs < THREADS; ofs <<= 1) {
        int t = (tid >= ofs) ? scan[tid - ofs] : 0;
        __syncthreads();
        scan[tid] += t;
        __syncthreads();
    }
    int excl = scan[tid] - seg;
    node_base[tid] = excl;
    if (tid < nn) {
        off[base_node + tid] = bob + excl;
        deg[base_node + tid] = c;
        rsd[base_node + tid] = rsqrtf(fmaxf((float)c, 1.0f));
        // absolute tile segment starts
        #pragma unroll
        for (int t = 0; t < T_TILES; ++t)
            tof[(size_t)(base_node + tid) * T_TILES + t] = bob + excl + bin_cnt[tid * T_TILES + t];
    }
    __syncthreads();
    // convert intra-node prefixes to absolute cursors
    #pragma unroll
    for (int t = 0; t < T_TILES; ++t) {
        int k = tid + t * THREADS;
        bin_cnt[k] += node_base[k >> 3];    // k/T_TILES = node slot
    }
    __syncthreads();
    for (int k = tid; k < count; k += THREADS) {
        int p = stash[k];
        int key = ((p >> losh) << 3) | ((p & lomask) >> tsh);
        int sl = atomicAdd(&bin_cnt[key], 1);   // LDS atomic
        ent[bob + sl] = p & lomask;
    }
}

// ---------------- fp32 table -> fp16 ----------------
__global__ void conv16(const float* __restrict__ src, __half* __restrict__ dst, int n4) {
    int stride = gridDim.x * blockDim.x;
    for (int i = blockIdx.x * blockDim.x + threadIdx.x; i < n4; i += stride) {
        float4 v = *reinterpret_cast<const float4*>(src + (size_t)i * 4);
        __half2 h0 = __float22half2_rn(make_float2(v.x, v.y));
        __half2 h1 = __float22half2_rn(make_float2(v.z, v.w));
        uint2 st;
        st.x = *reinterpret_cast<unsigned*>(&h0);
        st.y = *reinterpret_cast<unsigned*>(&h1);
        *reinterpret_cast<uint2*>(dst + (size_t)i * 4) = st;
    }
}

// ---------------- tile-phased propagation: tile loop OUTER, K nodes/group ----------------
// All ~1172 blocks are co-resident; every group processes only tile-t entries in
// phase t, so the machine-wide gather window is ~2.4MB (item-tile + user-tile),
// L2-resident per XCD. Accumulators live in registers (KNODES x 8 fp32/lane).
__global__ __launch_bounds__(THREADS, 4)
void prop16t(const __half* __restrict__ x,
             const int* __restrict__ tofu, const int* __restrict__ tofi,
             const int* __restrict__ offu, const int* __restrict__ offi,
             const int* __restrict__ du, const int* __restrict__ di,
             const float* __restrict__ rsdu, const float* __restrict__ rsdi,
             const int* __restrict__ entu, const int* __restrict__ enti,
             __half* __restrict__ y, int nU, int N) {
    int g = threadIdx.x >> 3;
    int lane = threadIdx.x & 7;
    int node0 = (blockIdx.x * (THREADS >> 3) + g) * KNODES;
    const __half* srcI = x + ((size_t)nU << 6);   // item rows
    float acc[KNODES][8];
    #pragma unroll
    for (int k = 0; k < KNODES; ++k)
        #pragma unroll
        for (int j = 0; j < 8; ++j) acc[k][j] = 0.f;

    for (int t = 0; t < T_TILES; ++t) {
        #pragma unroll
        for (int k = 0; k < KNODES; ++k) {
            int node = node0 + k;
            if (node >= N) continue;
            const int* ent; const __half* src; const float* rsdn;
            int s, e;
            if (node < nU) {
                const int* tf = tofu + (size_t)node * T_TILES;
                s = tf[t];
                e = (t < T_TILES - 1) ? tf[t + 1] : offu[node] + du[node];
                ent = entu; src = srcI; rsdn = rsdi;
            } else {
                int i = node - nU;
                const int* tf = tofi + (size_t)i * T_TILES;
                s = tf[t];
                e = (t < T_TILES - 1) ? tf[t + 1] : offi[i] + di[i];
                ent = enti; src = x; rsdn = rsdu;
            }
            for (int k0 = s; k0 < e; k0 += 8) {
                int me = (k0 + lane < e) ? ent[k0 + lane] : 0;
                #pragma unroll
                for (int j = 0; j < 8; ++j) {
                    if (k0 + j < e) {
                        int nbr = __shfl(me, j, 8);
                        float w = rsdn[nbr];
                        uint4 r = *reinterpret_cast<const uint4*>(src + ((size_t)nbr << 6) + (lane << 3));
                        __half2 h0 = *reinterpret_cast<__half2*>(&r.x);
                        __half2 h1 = *reinterpret_cast<__half2*>(&r.y);
                        __half2 h2 = *reinterpret_cast<__half2*>(&r.z);
                        __half2 h3 = *reinterpret_cast<__half2*>(&r.w);
                        float2 f0 = __half22float2(h0), f1 = __half22float2(h1);
                        float2 f2 = __half22float2(h2), f3 = __half22float2(h3);
                        acc[k][0] += w * f0.x; acc[k][1] += w * f0.y;
                        acc[k][2] += w * f1.x; acc[k][3] += w * f1.y;
                        acc[k][4] += w * f2.x; acc[k][5] += w * f2.y;
                        acc[k][6] += w * f3.x; acc[k][7] += w * f3.y;
                    }
                }
            }
        }
        __syncthreads();   // tile phase alignment within block
    }
    #pragma unroll
    for (int k = 0; k < KNODES; ++k) {
        int node = node0 + k;
        if (node >= N) continue;
        float rs = (node < nU) ? rsdu[node] : rsdi[node - nU];
        __half2 o0 = __float22half2_rn(make_float2(acc[k][0] * rs, acc[k][1] * rs));
        __half2 o1 = __float22half2_rn(make_float2(acc[k][2] * rs, acc[k][3] * rs));
        __half2 o2 = __float22half2_rn(make_float2(acc[k][4] * rs, acc[k][5] * rs));
        __half2 o3 = __float22half2_rn(make_float2(acc[k][6] * rs, acc[k][7] * rs));
        uint4 st;
        st.x = *reinterpret_cast<unsigned*>(&o0);
        st.y = *reinterpret_cast<unsigned*>(&o1);
        st.z = *reinterpret_cast<unsigned*>(&o2);
        st.w = *reinterpret_cast<unsigned*>(&o3);
        *reinterpret_cast<uint4*>(y + ((size_t)node << 6) + (lane << 3)) = st;
    }
}

// ---------------- selective layer-3: gather x2-neighborhood of selected rows only ----------------
__global__ void prop_sel(const __half* __restrict__ x,
                         const int* __restrict__ users, const int* __restrict__ pos,
                         const int* __restrict__ neg,
                         const int* __restrict__ offu, const int* __restrict__ offi,
                         const int* __restrict__ du, const int* __restrict__ di,
                         const float* __restrict__ rsdu, const float* __restrict__ rsdi,
                         const int* __restrict__ entu, const int* __restrict__ enti,
                         float* __restrict__ sel, int B, int nU) {
    int r = blockIdx.x * (THREADS >> 3) + (threadIdx.x >> 3);
    int lane = threadIdx.x & 7;
    if (r >= 3 * B) return;
    int which = r / B, b = r - which * B;
    const int* ent; const __half* src; const float* rsdn;
    int beg, dg; float rs;
    if (which == 0) {
        int u = users[b];
        beg = offu[u]; dg = du[u]; rs = rsdu[u];
        ent = entu; src = x + ((size_t)nU << 6); rsdn = rsdi;
    } else {
        int i = (which == 1) ? pos[b] : neg[b];
        beg = offi[i]; dg = di[i]; rs = rsdi[i];
        ent = enti; src = x; rsdn = rsdu;
    }
    float a0=0,a1=0,a2=0,a3=0,a4=0,a5=0,a6=0,a7=0;
    for (int k0 = 0; k0 < dg; k0 += 8) {
        int me = (k0 + lane < dg) ? ent[beg + k0 + lane] : 0;
        #pragma unroll
        for (int j = 0; j < 8; ++j) {
            if (k0 + j < dg) {
                int nbr = __shfl(me, j, 8);
                float w = rsdn[nbr];
                uint4 rv = *reinterpret_cast<const uint4*>(src + ((size_t)nbr << 6) + (lane << 3));
                __half2 h0 = *reinterpret_cast<__half2*>(&rv.x);
                __half2 h1 = *reinterpret_cast<__half2*>(&rv.y);
                __half2 h2 = *reinterpret_cast<__half2*>(&rv.z);
                __half2 h3 = *reinterpret_cast<__half2*>(&rv.w);
                float2 f0 = __half22float2(h0), f1 = __half22float2(h1);
                float2 f2 = __half22float2(h2), f3 = __half22float2(h3);
                a0 += w * f0.x; a1 += w * f0.y; a2 += w * f1.x; a3 += w * f1.y;
                a4 += w * f2.x; a5 += w * f2.y; a6 += w * f3.x; a7 += w * f3.y;
            }
        }
    }
    float* s = sel + ((size_t)r << 6) + (lane << 3);
    float4 d0 = *reinterpret_cast<float4*>(s);
    float4 d1 = *reinterpret_cast<float4*>(s + 4);
    d0.x += rs * a0; d0.y += rs * a1; d0.z += rs * a2; d0.w += rs * a3;
    d1.x += rs * a4; d1.y += rs * a5; d1.z += rs * a6; d1.w += rs * a7;
    *reinterpret_cast<float4*>(s) = d0;
    *reinterpret_cast<float4*>(s + 4) = d1;
}

// ---------------- layer-0 selected rows (fp32 tables) ----------------
__global__ void sel_init(const float* __restrict__ ut, const float* __restrict__ it,
                         const int* __restrict__ users, const int* __restrict__ pos,
                         const int* __restrict__ neg, float* __restrict__ sel, int B) {
    int r = blockIdx.x * (THREADS >> 4) + (threadIdx.x >> 4);
    int t = threadIdx.x & 15;
    if (r >= 3 * B) return;
    int which = r / B, b = r - which * B;
    const float* base; int idx;
    if (which == 0)      { base = ut; idx = users[b]; }
    else if (which == 1) { base = it; idx = pos[b]; }
    else                 { base = it; idx = neg[b]; }
    float4 v = *reinterpret_cast<const float4*>(base + ((size_t)idx << 6) + t * 4);
    *reinterpret_cast<float4*>(sel + ((size_t)r << 6) + t * 4) = v;
}

// ---------------- accumulate selected rows from fp16 layer output ----------------
__global__ void sel_acc16(const __half* __restrict__ x,
                          const int* __restrict__ users, const int* __restrict__ pos,
                          const int* __restrict__ neg, float* __restrict__ sel, int B, int nU) {
    int r = blockIdx.x * (THREADS >> 3) + (threadIdx.x >> 3);
    int lane = threadIdx.x & 7;
    if (r >= 3 * B) return;
    int which = r / B, b = r - which * B;
    size_t row;
    if (which == 0)      row = (size_t)users[b];
    else if (which == 1) row = (size_t)nU + pos[b];
    else                 row = (size_t)nU + neg[b];
    uint4 rv = *reinterpret_cast<const uint4*>(x + (row << 6) + (lane << 3));
    __half2 h0 = *reinterpret_cast<__half2*>(&rv.x);
    __half2 h1 = *reinterpret_cast<__half2*>(&rv.y);
    __half2 h2 = *reinterpret_cast<__half2*>(&rv.z);
    __half2 h3 = *reinterpret_cast<__half2*>(&rv.w);
    float2 f0 = __half22float2(h0), f1 = __half22float2(h1);
    float2 f2 = __half22float2(h2), f3 = __half22float2(h3);
    float* s = sel + ((size_t)r << 6) + (lane << 3);
    float4 d0 = *reinterpret_cast<float4*>(s);
    float4 d1 = *reinterpret_cast<float4*>(s + 4);
    d0.x += f0.x; d0.y += f0.y; d0.z += f1.x; d0.w += f1.y;
    d1.x += f2.x; d1.y += f2.y; d1.z += f3.x; d1.w += f3.y;
    *reinterpret_cast<float4*>(s) = d0;
    *reinterpret_cast<float4*>(s + 4) = d1;
}

// ---------------- final scores ----------------
__global__ void score(const float* __restrict__ sel, float* __restrict__ out, int B) {
    int b = blockIdx.x * (THREADS >> 6) + (threadIdx.x >> 6);
    int lane = threadIdx.x & 63;
    if (b >= B) return;
    float u = sel[((size_t)b << 6) + lane];
    float p = sel[((size_t)(B + b) << 6) + lane];
    float n = sel[((size_t)(2 * B + b) << 6) + lane];
    float ps = u * p, ns = u * n;
    for (int ofs = 32; ofs; ofs >>= 1) {
        ps += __shfl_down(ps, ofs);
        ns += __shfl_down(ns, ofs);
    }
    if (lane == 0) {
        out[b]     = ps * (1.0f / 16.0f);
        out[B + b] = ns * (1.0f / 16.0f);
    }
}

// ---------------- regularization loss ----------------
__global__ void regk(const float* __restrict__ ut, const float* __restrict__ it,
                     const int* __restrict__ users, const int* __restrict__ pos,
                     const int* __restrict__ neg,
                     float* __restrict__ out_reg, int B, float scale) {
    int total = 3 * B * 64;
    float s = 0.f;
    int stride = gridDim.x * blockDim.x;
    for (int idx = blockIdx.x * blockDim.x + threadIdx.x; idx < total; idx += stride) {
        int r = idx >> 6, d = idx & 63;
        int which = r / B, b = r - which * B;
        float v;
        if (which == 0)      v = ut[((size_t)users[b] << 6) + d];
        else if (which == 1) v = it[((size_t)pos[b] << 6) + d];
        else                 v = it[((size_t)neg[b] << 6) + d];
        s += v * v;
    }
    for (int ofs = 32; ofs; ofs >>= 1) s += __shfl_down(s, ofs);
    __shared__ float sh[4];
    int lane = threadIdx.x & 63, wid = threadIdx.x >> 6;
    if (lane == 0) sh[wid] = s;
    __syncthreads();
    if (threadIdx.x == 0) {
        float tot = 0.f;
        for (int i = 0; i < (int)(blockDim.x >> 6); ++i) tot += sh[i];
        atomicAdd(out_reg, tot * scale);
    }
}

extern "C" void kernel_launch(void* const* d_in, const int* in_sizes, int n_in,
                              void* d_out, int out_size, void* d_ws, size_t ws_size,
                              hipStream_t stream) {
    const float* ut   = (const float*)d_in[0];
    const float* it   = (const float*)d_in[1];
    const int* eu     = (const int*)d_in[2];
    const int* ei     = (const int*)d_in[3];
    const int* users  = (const int*)d_in[4];
    const int* pos    = (const int*)d_in[5];
    const int* neg    = (const int*)d_in[6];
    int nU = in_sizes[0] / 64;
    int nI = in_sizes[1] / 64;
    int E  = in_sizes[2];
    int B  = in_sizes[4];
    int N  = nU + nI;
    float* out = (float*)d_out;

    int nbu = (nU + 255) >> SH_U;   // 391
    int nbi = (nI + 127) >> SH_I;   // 391

    char* ws = (char*)d_ws;
    size_t cursor = 0;
    auto alloc = [&](size_t bytes) -> void* {
        cursor = (cursor + 255) & ~(size_t)255;
        void* p = ws + cursor;
        cursor += bytes;
        return p;
    };
    int*   bcnt_u = (int*)alloc((size_t)nbu * CPAD * 4);
    int*   bcnt_i = (int*)alloc((size_t)nbi * CPAD * 4);
    int*   curs   = (int*)alloc(2 * 4);
    size_t zero_span = cursor;                    // bcnt_u..curs zeroed in one memset
    int*   bo_u = (int*)alloc((size_t)nbu * 4);
    int*   bo_i = (int*)alloc((size_t)nbi * 4);
    int*   binu = (int*)alloc((size_t)nbu * CAP * 4);
    int*   bini = (int*)alloc((size_t)nbi * CAP * 4);
    int*   offu = (int*)alloc((size_t)nU * 4);
    int*   offi = (int*)alloc((size_t)nI * 4);
    int*   du   = (int*)alloc((size_t)nU * 4);
    int*   di   = (int*)alloc((size_t)nI * 4);
    float* rsdu = (float*)alloc((size_t)nU * 4);
    float* rsdi = (float*)alloc((size_t)nI * 4);
    int*   tofu = (int*)alloc((size_t)nU * T_TILES * 4);
    int*   tofi = (int*)alloc((size_t)nI * T_TILES * 4);
    int*   entu = (int*)alloc(((size_t)E + (size_t)nbu * 256 * 16) * 4);
    int*   enti = (int*)alloc(((size_t)E + (size_t)nbi * 128 * 16) * 4);
    __half* xA  = (__half*)alloc((size_t)N * 64 * 2);
    __half* xB  = (__half*)alloc((size_t)N * 64 * 2);
    float* sel  = (float*)alloc((size_t)3 * B * 64 * 4);

    hipMemsetAsync(d_ws, 0, zero_span, stream);
    hipMemsetAsync(out + 2 * B, 0, sizeof(float), stream);

    // fp16 tables (layer-1 input)
    conv16<<<2048, THREADS, 0, stream>>>(ut, xA, nU * 16);
    conv16<<<2048, THREADS, 0, stream>>>(it, xA + ((size_t)nU << 6), nI * 16);

    // graph build: bin -> bucket_off -> place (tile-sorted adjacency + tileoff)
    int nchunks = (E + BIN_C - 1) / BIN_C;
    bin_kernel<<<nchunks, THREADS, 0, stream>>>(eu, ei, bcnt_u, bcnt_i, binu, bini, E, nbu, nbi);
    bucket_off<<<(nbu + THREADS - 1) / THREADS, THREADS, 0, stream>>>(bcnt_u, bo_u, curs, nbu, 256 * 16);
    bucket_off<<<(nbi + THREADS - 1) / THREADS, THREADS, 0, stream>>>(bcnt_i, bo_i, curs + 1, nbi, 128 * 16);
    place<<<nbu + nbi, THREADS, 0, stream>>>(bcnt_u, bcnt_i, bo_u, bo_i, binu, bini,
                                             offu, offi, du, di, rsdu, rsdi, entu, enti,
                                             tofu, tofi, nbu, nU, nI);

    // layer 0 selected rows
    int gridSel16 = (3 * B * 8 + THREADS - 1) / THREADS;
    sel_init<<<(3 * B + 15) / 16, THREADS, 0, stream>>>(ut, it, users, pos, neg, sel, B);

    // layers 1,2 full tile-phased propagation; layer 3 selective
    int nodesPerBlock = (THREADS >> 3) * KNODES;   // 128
    int gridProp = (N + nodesPerBlock - 1) / nodesPerBlock;
    prop16t<<<gridProp, THREADS, 0, stream>>>(xA, tofu, tofi, offu, offi, du, di,
                                              rsdu, rsdi, entu, enti, xB, nU, N);
    sel_acc16<<<gridSel16, THREADS, 0, stream>>>(xB, users, pos, neg, sel, B, nU);
    prop16t<<<gridProp, THREADS, 0, stream>>>(xB, tofu, tofi, offu, offi, du, di,
                                              rsdu, rsdi, entu, enti, xA, nU, N);
    sel_acc16<<<gridSel16, THREADS, 0, stream>>>(xA, users, pos, neg, sel, B, nU);
    prop_sel<<<gridSel16, THREADS, 0, stream>>>(xA, users, pos, neg, offu, offi, du, di,
                                                rsdu, rsdi, entu, enti, sel, B, nU);

    // scores + reg
    score<<<(B + 3) / 4, THREADS, 0, stream>>>(sel, out, B);
    regk<<<256, THREADS, 0, stream>>>(ut, it, users, pos, neg, out + 2 * B, B, 1e-4f / (float)B);
}

// Round 10
// 284.743 us; speedup vs baseline: 1.3918x; 1.3918x over previous
//
#include <hip/hip_runtime.h>
#include <hip/hip_fp16.h>

#define THREADS 256
#define BIN_C 4096           // edges per block chunk (16/thread, held in registers)
#define NBMAX 400            // LDS histogram size (>= bucket count 391)
#define CAP 4608             // bucket capacity (mean 4090, sd ~64 -> 8 sigma slack)
#define SH_U 8               // 256 user nodes / bucket
#define SH_I 7               // 128 item nodes / bucket
#define CPAD 16              // one 64B line per bucket counter
#define T_TILES 8            // neighbor tiles (adjacency tile-sort, weak but positive)
#define TSH_U 13
#define TSH_I 14

// ---------------- bin: block-aggregated bucket scatter ----------------
__global__ void bin_kernel(const int* __restrict__ eu, const int* __restrict__ ei,
                           int* __restrict__ bcnt_u, int* __restrict__ bcnt_i,
                           int* __restrict__ binu, int* __restrict__ bini,
                           int E, int nbu, int nbi) {
    __shared__ int hist_u[NBMAX], hist_i[NBMAX];
    __shared__ int base_u[NBMAX], base_i[NBMAX];
    int tid = threadIdx.x;
    int e0 = blockIdx.x * BIN_C;
    if (e0 >= E) return;
    int cnt = min(BIN_C, E - e0);

    for (int b = tid; b < NBMAX; b += THREADS) { hist_u[b] = 0; hist_i[b] = 0; }
    __syncthreads();

    int u[16], v[16];
    #pragma unroll
    for (int j = 0; j < 16; ++j) {
        int k = tid + j * THREADS;
        if (k < cnt) { u[j] = eu[e0 + k]; v[j] = ei[e0 + k]; }
        else         { u[j] = -1; v[j] = -1; }
    }
    #pragma unroll
    for (int j = 0; j < 16; ++j) {
        if (u[j] >= 0) {
            atomicAdd(&hist_u[u[j] >> SH_U], 1);
            atomicAdd(&hist_i[v[j] >> SH_I], 1);
        }
    }
    __syncthreads();
    for (int b = tid; b < NBMAX; b += THREADS) {
        int cu = hist_u[b], ci = hist_i[b];
        base_u[b] = (cu > 0 && b < nbu) ? atomicAdd(&bcnt_u[(size_t)b * CPAD], cu) : 0;
        base_i[b] = (ci > 0 && b < nbi) ? atomicAdd(&bcnt_i[(size_t)b * CPAD], ci) : 0;
        hist_u[b] = 0; hist_i[b] = 0;      // reuse as intra-block cursors
    }
    __syncthreads();
    #pragma unroll
    for (int j = 0; j < 16; ++j) {
        if (u[j] >= 0) {
            int bu = u[j] >> SH_U;
            int pu = base_u[bu] + atomicAdd(&hist_u[bu], 1);
            if (pu < CAP) binu[(size_t)bu * CAP + pu] = ((u[j] & 255) << 16) | v[j];  // i < 2^16
            int bi = v[j] >> SH_I;
            int pi = base_i[bi] + atomicAdd(&hist_i[bi], 1);
            if (pi < CAP) bini[(size_t)bi * CAP + pi] = ((v[j] & 127) << 17) | u[j];  // u < 2^17
        }
    }
}

// ---------------- place: counting sort by (node, nbr_tile) -> tile-sorted CSR ----------------
// Region reservation fused in (atomicAdd on curs[dir]) -> no bucket_off pass.
// Wave-shfl scan (1 barrier) replaces the 32-barrier Hillis-Steele.
__global__ void place(const int* __restrict__ bcnt_u, const int* __restrict__ bcnt_i,
                      const int* __restrict__ binu, const int* __restrict__ bini,
                      int* __restrict__ offu, int* __restrict__ offi,
                      int* __restrict__ du, int* __restrict__ di,
                      float* __restrict__ rsdu, float* __restrict__ rsdi,
                      int* __restrict__ entu, int* __restrict__ enti,
                      int* __restrict__ curs,
                      int nbu, int nU, int nI) {
    __shared__ int stash[CAP];
    __shared__ int bin_cnt[THREADS * T_TILES];   // 2048 bins (cnt -> prefix -> cursor)
    __shared__ int node_base[THREADS];
    __shared__ int wsum[4];
    __shared__ int bob_sh;
    int b = blockIdx.x;
    bool isU = (b < nbu);
    const int* bin; int base_node, nn, count;
    int *off, *deg, *ent; float* rsd;
    int losh, tsh, lomask;
    if (isU) {
        bin = binu + (size_t)b * CAP;
        base_node = b << SH_U; nn = min(256, nU - base_node);
        count = min(bcnt_u[(size_t)b * CPAD], CAP);
        off = offu; deg = du; rsd = rsdu; ent = entu;
        losh = 16; tsh = TSH_U; lomask = 0xFFFF;
    } else {
        int b2 = b - nbu;
        bin = bini + (size_t)b2 * CAP;
        base_node = b2 << SH_I; nn = min(128, nI - base_node);
        count = min(bcnt_i[(size_t)b2 * CPAD], CAP);
        off = offi; deg = di; rsd = rsdi; ent = enti;
        losh = 17; tsh = TSH_I; lomask = 0x1FFFF;
    }
    int tid = threadIdx.x;
    #pragma unroll
    for (int t = 0; t < T_TILES; ++t) bin_cnt[tid + t * THREADS] = 0;
    __syncthreads();
    for (int k = tid; k < count; k += THREADS) {
        int p = bin[k];
        stash[k] = p;
        int key = ((p >> losh) << 3) | ((p & lomask) >> tsh);
        atomicAdd(&bin_cnt[key], 1);
    }
    __syncthreads();
    // intra-node exclusive prefix over the node's 8 tile-bins; c = node degree
    int c = 0;
    {
        int base = tid * T_TILES;
        #pragma unroll
        for (int t = 0; t < T_TILES; ++t) {
            int v = bin_cnt[base + t];
            bin_cnt[base + t] = c;
            c += v;
        }
    }
    int seg = (c + 15) & ~15;               // 64B-align per-node segment
    // wave-level inclusive scan of seg
    int lane = tid & 63, wid = tid >> 6;
    int inc = seg;
    #pragma unroll
    for (int ofs = 1; ofs < 64; ofs <<= 1) {
        int t = __shfl_up(inc, ofs);
        if (lane >= ofs) inc += t;
    }
    if (lane == 63) wsum[wid] = inc;
    __syncthreads();
    int wofs = 0;
    #pragma unroll
    for (int w = 0; w < 4; ++w) wofs += (w < wid) ? wsum[w] : 0;
    int incl = inc + wofs;
    int excl = incl - seg;
    if (tid == THREADS - 1) bob_sh = atomicAdd(&curs[isU ? 0 : 1], incl);  // incl == padded total
    __syncthreads();
    int bob = bob_sh;
    node_base[tid] = excl;
    if (tid < nn) {
        off[base_node + tid] = bob + excl;
        deg[base_node + tid] = c;
        rsd[base_node + tid] = rsqrtf(fmaxf((float)c, 1.0f));
    }
    __syncthreads();
    // convert intra-node prefixes to absolute cursors
    #pragma unroll
    for (int t = 0; t < T_TILES; ++t) {
        int k = tid + t * THREADS;
        bin_cnt[k] += node_base[k >> 3];
    }
    __syncthreads();
    for (int k = tid; k < count; k += THREADS) {
        int p = stash[k];
        int key = ((p >> losh) << 3) | ((p & lomask) >> tsh);
        int sl = atomicAdd(&bin_cnt[key], 1);   // LDS atomic
        ent[bob + sl] = p & lomask;
    }
}

// ---------------- fp32 tables (both) -> fp16 ----------------
__global__ void conv16all(const float* __restrict__ ut, const float* __restrict__ it,
                          __half* __restrict__ dst, int nU16, int ntot16) {
    int stride = gridDim.x * blockDim.x;
    for (int i = blockIdx.x * blockDim.x + threadIdx.x; i < ntot16; i += stride) {
        const float* src = (i < nU16) ? (ut + (size_t)i * 4) : (it + (size_t)(i - nU16) * 4);
        float4 v = *reinterpret_cast<const float4*>(src);
        __half2 h0 = __float22half2_rn(make_float2(v.x, v.y));
        __half2 h1 = __float22half2_rn(make_float2(v.z, v.w));
        uint2 st;
        st.x = *reinterpret_cast<unsigned*>(&h0);
        st.y = *reinterpret_cast<unsigned*>(&h1);
        *reinterpret_cast<uint2*>(dst + (size_t)i * 4) = st;
    }
}

// ---------------- propagation layer (R8 formulation: 62us known-best) ----------------
__global__ void prop16(const __half* __restrict__ x,
                       const int* __restrict__ offu, const int* __restrict__ offi,
                       const int* __restrict__ du, const int* __restrict__ di,
                       const float* __restrict__ rsdu, const float* __restrict__ rsdi,
                       const int* __restrict__ entu, const int* __restrict__ enti,
                       __half* __restrict__ y, int nU, int N) {
    int node = blockIdx.x * (THREADS >> 3) + (threadIdx.x >> 3);
    int lane = threadIdx.x & 7;
    if (node >= N) return;
    const int* ent; const __half* src; const float* rsdn;
    int beg, dg; float rs;
    if (node < nU) {
        beg = offu[node]; dg = du[node]; rs = rsdu[node];
        ent = entu; src = x + ((size_t)nU << 6); rsdn = rsdi;
    } else {
        int i = node - nU;
        beg = offi[i]; dg = di[i]; rs = rsdi[i];
        ent = enti; src = x; rsdn = rsdu;
    }
    float a0=0,a1=0,a2=0,a3=0,a4=0,a5=0,a6=0,a7=0;
    for (int k0 = 0; k0 < dg; k0 += 8) {
        int me = (k0 + lane < dg) ? ent[beg + k0 + lane] : 0;
        #pragma unroll
        for (int j = 0; j < 8; ++j) {
            if (k0 + j < dg) {
                int nbr = __shfl(me, j, 8);
                float w = rsdn[nbr];
                uint4 r = *reinterpret_cast<const uint4*>(src + ((size_t)nbr << 6) + (lane << 3));
                __half2 h0 = *reinterpret_cast<__half2*>(&r.x);
                __half2 h1 = *reinterpret_cast<__half2*>(&r.y);
                __half2 h2 = *reinterpret_cast<__half2*>(&r.z);
                __half2 h3 = *reinterpret_cast<__half2*>(&r.w);
                float2 f0 = __half22float2(h0), f1 = __half22float2(h1);
                float2 f2 = __half22float2(h2), f3 = __half22float2(h3);
                a0 += w * f0.x; a1 += w * f0.y; a2 += w * f1.x; a3 += w * f1.y;
                a4 += w * f2.x; a5 += w * f2.y; a6 += w * f3.x; a7 += w * f3.y;
            }
        }
    }
    __half2 o0 = __float22half2_rn(make_float2(a0 * rs, a1 * rs));
    __half2 o1 = __float22half2_rn(make_float2(a2 * rs, a3 * rs));
    __half2 o2 = __float22half2_rn(make_float2(a4 * rs, a5 * rs));
    __half2 o3 = __float22half2_rn(make_float2(a6 * rs, a7 * rs));
    uint4 st;
    st.x = *reinterpret_cast<unsigned*>(&o0);
    st.y = *reinterpret_cast<unsigned*>(&o1);
    st.z = *reinterpret_cast<unsigned*>(&o2);
    st.w = *reinterpret_cast<unsigned*>(&o3);
    *reinterpret_cast<uint4*>(y + ((size_t)node << 6) + (lane << 3)) = st;
}

// ---------------- fused: sel += x2[row] + rs*sum(rsd[nbr]*x2[nbr])  (layer2-acc + layer3-sel) ----------------
__global__ void prop_sel_acc(const __half* __restrict__ x,
                             const int* __restrict__ users, const int* __restrict__ pos,
                             const int* __restrict__ neg,
                             const int* __restrict__ offu, const int* __restrict__ offi,
                             const int* __restrict__ du, const int* __restrict__ di,
                             const float* __restrict__ rsdu, const float* __restrict__ rsdi,
                             const int* __restrict__ entu, const int* __restrict__ enti,
                             float* __restrict__ sel, int B, int nU) {
    int r = blockIdx.x * (THREADS >> 3) + (threadIdx.x >> 3);
    int lane = threadIdx.x & 7;
    if (r >= 3 * B) return;
    int which = r / B, b = r - which * B;
    const int* ent; const __half* src; const float* rsdn;
    int beg, dg; float rs; size_t selfrow;
    if (which == 0) {
        int u = users[b];
        beg = offu[u]; dg = du[u]; rs = rsdu[u];
        ent = entu; src = x + ((size_t)nU << 6); rsdn = rsdi;
        selfrow = (size_t)u << 6;
    } else {
        int i = (which == 1) ? pos[b] : neg[b];
        beg = offi[i]; dg = di[i]; rs = rsdi[i];
        ent = enti; src = x; rsdn = rsdu;
        selfrow = (size_t)(nU + i) << 6;
    }
    float a0=0,a1=0,a2=0,a3=0,a4=0,a5=0,a6=0,a7=0;
    for (int k0 = 0; k0 < dg; k0 += 8) {
        int me = (k0 + lane < dg) ? ent[beg + k0 + lane] : 0;
        #pragma unroll
        for (int j = 0; j < 8; ++j) {
            if (k0 + j < dg) {
                int nbr = __shfl(me, j, 8);
                float w = rsdn[nbr];
                uint4 rv = *reinterpret_cast<const uint4*>(src + ((size_t)nbr << 6) + (lane << 3));
                __half2 h0 = *reinterpret_cast<__half2*>(&rv.x);
                __half2 h1 = *reinterpret_cast<__half2*>(&rv.y);
                __half2 h2 = *reinterpret_cast<__half2*>(&rv.z);
                __half2 h3 = *reinterpret_cast<__half2*>(&rv.w);
                float2 f0 = __half22float2(h0), f1 = __half22float2(h1);
                float2 f2 = __half22float2(h2), f3 = __half22float2(h3);
                a0 += w * f0.x; a1 += w * f0.y; a2 += w * f1.x; a3 += w * f1.y;
                a4 += w * f2.x; a5 += w * f2.y; a6 += w * f3.x; a7 += w * f3.y;
            }
        }
    }
    // self row (layer-2 contribution)
    uint4 rv = *reinterpret_cast<const uint4*>(x + selfrow + (lane << 3));
    __half2 h0 = *reinterpret_cast<__half2*>(&rv.x);
    __half2 h1 = *reinterpret_cast<__half2*>(&rv.y);
    __half2 h2 = *reinterpret_cast<__half2*>(&rv.z);
    __half2 h3 = *reinterpret_cast<__half2*>(&rv.w);
    float2 s0 = __half22float2(h0), s1 = __half22float2(h1);
    float2 s2 = __half22float2(h2), s3 = __half22float2(h3);
    float* s = sel + ((size_t)r << 6) + (lane << 3);
    float4 d0 = *reinterpret_cast<float4*>(s);
    float4 d1 = *reinterpret_cast<float4*>(s + 4);
    d0.x += s0.x + rs * a0; d0.y += s0.y + rs * a1;
    d0.z += s1.x + rs * a2; d0.w += s1.y + rs * a3;
    d1.x += s2.x + rs * a4; d1.y += s2.y + rs * a5;
    d1.z += s3.x + rs * a6; d1.w += s3.y + rs * a7;
    *reinterpret_cast<float4*>(s) = d0;
    *reinterpret_cast<float4*>(s + 4) = d1;
}

// ---------------- fused: sel = table rows (layer 0) + reg loss ----------------
__global__ void selreg(const float* __restrict__ ut, const float* __restrict__ it,
                       const int* __restrict__ users, const int* __restrict__ pos,
                       const int* __restrict__ neg,
                       float* __restrict__ sel, float* __restrict__ out_reg,
                       int B, float scale) {
    int r = blockIdx.x * (THREADS >> 4) + (threadIdx.x >> 4);
    int t = threadIdx.x & 15;
    float ssq = 0.f;
    if (r < 3 * B) {
        int which = r / B, b = r - which * B;
        const float* base; int idx;
        if (which == 0)      { base = ut; idx = users[b]; }
        else if (which == 1) { base = it; idx = pos[b]; }
        else                 { base = it; idx = neg[b]; }
        float4 v = *reinterpret_cast<const float4*>(base + ((size_t)idx << 6) + t * 4);
        *reinterpret_cast<float4*>(sel + ((size_t)r << 6) + t * 4) = v;
        ssq = v.x * v.x + v.y * v.y + v.z * v.z + v.w * v.w;
    }
    #pragma unroll
    for (int ofs = 32; ofs; ofs >>= 1) ssq += __shfl_down(ssq, ofs);
    if ((threadIdx.x & 63) == 0) atomicAdd(out_reg, ssq * scale);
}

// ---------------- accumulate selected rows from fp16 layer output ----------------
__global__ void sel_acc16(const __half* __restrict__ x,
                          const int* __restrict__ users, const int* __restrict__ pos,
                          const int* __restrict__ neg, float* __restrict__ sel, int B, int nU) {
    int r = blockIdx.x * (THREADS >> 3) + (threadIdx.x >> 3);
    int lane = threadIdx.x & 7;
    if (r >= 3 * B) return;
    int which = r / B, b = r - which * B;
    size_t row;
    if (which == 0)      row = (size_t)users[b];
    else if (which == 1) row = (size_t)nU + pos[b];
    else                 row = (size_t)nU + neg[b];
    uint4 rv = *reinterpret_cast<const uint4*>(x + (row << 6) + (lane << 3));
    __half2 h0 = *reinterpret_cast<__half2*>(&rv.x);
    __half2 h1 = *reinterpret_cast<__half2*>(&rv.y);
    __half2 h2 = *reinterpret_cast<__half2*>(&rv.z);
    __half2 h3 = *reinterpret_cast<__half2*>(&rv.w);
    float2 f0 = __half22float2(h0), f1 = __half22float2(h1);
    float2 f2 = __half22float2(h2), f3 = __half22float2(h3);
    float* s = sel + ((size_t)r << 6) + (lane << 3);
    float4 d0 = *reinterpret_cast<float4*>(s);
    float4 d1 = *reinterpret_cast<float4*>(s + 4);
    d0.x += f0.x; d0.y += f0.y; d0.z += f1.x; d0.w += f1.y;
    d1.x += f2.x; d1.y += f2.y; d1.z += f3.x; d1.w += f3.y;
    *reinterpret_cast<float4*>(s) = d0;
    *reinterpret_cast<float4*>(s + 4) = d1;
}

// ---------------- final scores ----------------
__global__ void score(const float* __restrict__ sel, float* __restrict__ out, int B) {
    int b = blockIdx.x * (THREADS >> 6) + (threadIdx.x >> 6);
    int lane = threadIdx.x & 63;
    if (b >= B) return;
    float u = sel[((size_t)b << 6) + lane];
    float p = sel[((size_t)(B + b) << 6) + lane];
    float n = sel[((size_t)(2 * B + b) << 6) + lane];
    float ps = u * p, ns = u * n;
    for (int ofs = 32; ofs; ofs >>= 1) {
        ps += __shfl_down(ps, ofs);
        ns += __shfl_down(ns, ofs);
    }
    if (lane == 0) {
        out[b]     = ps * (1.0f / 16.0f);
        out[B + b] = ns * (1.0f / 16.0f);
    }
}

extern "C" void kernel_launch(void* const* d_in, const int* in_sizes, int n_in,
                              void* d_out, int out_size, void* d_ws, size_t ws_size,
                              hipStream_t stream) {
    const float* ut   = (const float*)d_in[0];
    const float* it   = (const float*)d_in[1];
    const int* eu     = (const int*)d_in[2];
    const int* ei     = (const int*)d_in[3];
    const int* users  = (const int*)d_in[4];
    const int* pos    = (const int*)d_in[5];
    const int* neg    = (const int*)d_in[6];
    int nU = in_sizes[0] / 64;
    int nI = in_sizes[1] / 64;
    int E  = in_sizes[2];
    int B  = in_sizes[4];
    int N  = nU + nI;
    float* out = (float*)d_out;

    int nbu = (nU + 255) >> SH_U;   // 391
    int nbi = (nI + 127) >> SH_I;   // 391

    char* ws = (char*)d_ws;
    size_t cursor = 0;
    auto alloc = [&](size_t bytes) -> void* {
        cursor = (cursor + 255) & ~(size_t)255;
        void* p = ws + cursor;
        cursor += bytes;
        return p;
    };
    int*   bcnt_u = (int*)alloc((size_t)nbu * CPAD * 4);
    int*   bcnt_i = (int*)alloc((size_t)nbi * CPAD * 4);
    int*   curs   = (int*)alloc(2 * 4);
    size_t zero_span = cursor;                    // bcnt_u..curs zeroed in one memset
    int*   binu = (int*)alloc((size_t)nbu * CAP * 4);
    int*   bini = (int*)alloc((size_t)nbi * CAP * 4);
    int*   offu = (int*)alloc((size_t)nU * 4);
    int*   offi = (int*)alloc((size_t)nI * 4);
    int*   du   = (int*)alloc((size_t)nU * 4);
    int*   di   = (int*)alloc((size_t)nI * 4);
    float* rsdu = (float*)alloc((size_t)nU * 4);
    float* rsdi = (float*)alloc((size_t)nI * 4);
    int*   entu = (int*)alloc(((size_t)E + (size_t)nbu * 256 * 16) * 4);
    int*   enti = (int*)alloc(((size_t)E + (size_t)nbi * 128 * 16) * 4);
    __half* xA  = (__half*)alloc((size_t)N * 64 * 2);
    __half* xB  = (__half*)alloc((size_t)N * 64 * 2);
    float* sel  = (float*)alloc((size_t)3 * B * 64 * 4);

    hipMemsetAsync(d_ws, 0, zero_span, stream);
    hipMemsetAsync(out + 2 * B, 0, sizeof(float), stream);

    // fp16 tables (layer-1 input), one dispatch
    conv16all<<<2048, THREADS, 0, stream>>>(ut, it, xA, nU * 16, N * 16);

    // graph build: bin -> place (region reservation fused into place)
    int nchunks = (E + BIN_C - 1) / BIN_C;
    bin_kernel<<<nchunks, THREADS, 0, stream>>>(eu, ei, bcnt_u, bcnt_i, binu, bini, E, nbu, nbi);
    place<<<nbu + nbi, THREADS, 0, stream>>>(bcnt_u, bcnt_i, binu, bini,
                                             offu, offi, du, di, rsdu, rsdi, entu, enti,
                                             curs, nbu, nU, nI);

    // layer 0 selected rows + reg loss (fused)
    selreg<<<(3 * B + 15) / 16, THREADS, 0, stream>>>(ut, it, users, pos, neg, sel,
                                                      out + 2 * B, B, 1e-4f / (float)B);

    // layers 1,2 full propagation; layer-2 acc + layer-3 selective fused
    int gridSel16 = (3 * B * 8 + THREADS - 1) / THREADS;
    int gridProp = (N * 8 + THREADS - 1) / THREADS;
    prop16<<<gridProp, THREADS, 0, stream>>>(xA, offu, offi, du, di, rsdu, rsdi, entu, enti, xB, nU, N);
    sel_acc16<<<gridSel16, THREADS, 0, stream>>>(xB, users, pos, neg, sel, B, nU);
    prop16<<<gridProp, THREADS, 0, stream>>>(xB, offu, offi, du, di, rsdu, rsdi, entu, enti, xA, nU, N);
    prop_sel_acc<<<gridSel16, THREADS, 0, stream>>>(xA, users, pos, neg, offu, offi, du, di,
                                                    rsdu, rsdi, entu, enti, sel, B, nU);

    // scores
    score<<<(B + 3) / 4, THREADS, 0, stream>>>(sel, out, B);
}

// Round 11
// 280.648 us; speedup vs baseline: 1.4121x; 1.0146x over previous
//
#include <hip/hip_runtime.h>
#include <hip/hip_fp16.h>

#define THREADS 256
#define BIN_C2 4096          // edges per chunk; chunk owns a private 4096-entry region/dir
#define NBMAX 392            // >= bucket count 391
#define CAP 4608             // place stash capacity (mean 4092, 8 sigma slack)
#define SH_U 8               // 256 user nodes / bucket
#define SH_I 7               // 128 item nodes / bucket
#define CPAD 16              // one 64B line per global counter
#define T_TILES 8            // neighbor tiles (adjacency tile-sort)
#define TSH_U 13
#define TSH_I 14

// ---------------- binpack: per-chunk bucket-sorted private regions ----------------
// Chunk c, direction d: LDS hist -> scan -> contiguous bucket-sorted write into
// reg[c*BIN_C2 ...]. Every output 64B line is written entirely by this block
// (no shared cursor tips -> no partial-line writebacks), zero global atomics.
__global__ void binpack(const int* __restrict__ eu, const int* __restrict__ ei,
                        int* __restrict__ regu, int* __restrict__ regi,
                        int* __restrict__ sTu, int* __restrict__ sTi,
                        int E, int nbu, int nbi) {
    int c = blockIdx.x;
    bool isU = (blockIdx.y == 0);
    const int* key   = isU ? eu : ei;
    const int* other = isU ? ei : eu;
    int nb   = isU ? nbu : nbi;
    int sh   = isU ? SH_U : SH_I;
    int losh = isU ? 16 : 17;
    int lomsk = (1 << sh) - 1;
    int* reg = isU ? regu : regi;
    int* sT  = (isU ? sTu : sTi) + (size_t)c * (NBMAX);   // row c, NBMAX >= nb+1
    __shared__ int hist[NBMAX];
    __shared__ int wsum[4];
    int tid = threadIdx.x;
    int e0 = c * BIN_C2;
    int cnt = min(BIN_C2, E - e0);
    if (cnt <= 0) return;
    for (int b = tid; b < nb; b += THREADS) hist[b] = 0;
    __syncthreads();
    for (int k = tid; k < cnt; k += THREADS)
        atomicAdd(&hist[key[e0 + k] >> sh], 1);
    __syncthreads();
    // exclusive scan over nb bins (2 bins/thread, wave scan)
    int b0 = tid * 2;
    int v0 = (b0 < nb)     ? hist[b0]     : 0;
    int v1 = (b0 + 1 < nb) ? hist[b0 + 1] : 0;
    int s2 = v0 + v1;
    int lane = tid & 63, wid = tid >> 6;
    int inc = s2;
    #pragma unroll
    for (int ofs = 1; ofs < 64; ofs <<= 1) {
        int t = __shfl_up(inc, ofs);
        if (lane >= ofs) inc += t;
    }
    if (lane == 63) wsum[wid] = inc;
    __syncthreads();
    int wofs = 0;
    #pragma unroll
    for (int w = 0; w < 4; ++w) wofs += (w < wid) ? wsum[w] : 0;
    int excl = inc - s2 + wofs;
    __syncthreads();                 // hist reads done; safe to overwrite
    if (b0 < nb)     { hist[b0] = excl;          sT[b0] = excl; }
    if (b0 + 1 < nb) { hist[b0 + 1] = excl + v0; sT[b0 + 1] = excl + v0; }
    if (tid == THREADS - 1) sT[nb] = cnt;
    __syncthreads();
    // scatter into private region, bucket-sorted
    for (int k = tid; k < cnt; k += THREADS) {
        int kn = key[e0 + k];
        int o  = other[e0 + k];
        int b  = kn >> sh;
        int p  = ((kn & lomsk) << losh) | o;
        int pos = atomicAdd(&hist[b], 1);        // LDS cursor
        reg[(size_t)c * BIN_C2 + pos] = p;
    }
}

// ---------------- place: gather chunk segments -> counting sort by (node,tile) ----------------
__global__ void place(const int* __restrict__ regu, const int* __restrict__ regi,
                      const int* __restrict__ sTu, const int* __restrict__ sTi,
                      int* __restrict__ offu, int* __restrict__ offi,
                      int* __restrict__ du, int* __restrict__ di,
                      float* __restrict__ rsdu, float* __restrict__ rsdi,
                      int* __restrict__ entu, int* __restrict__ enti,
                      int* __restrict__ curs,
                      int nbu, int nU, int nI, int nchunks) {
    __shared__ int stash[CAP];
    __shared__ int bin_cnt[THREADS * T_TILES];
    __shared__ int node_base[THREADS];
    __shared__ int wsum[4];
    __shared__ int bob_sh;
    __shared__ int scursor;
    int b = blockIdx.x;
    bool isU = (b < nbu);
    int bidx = isU ? b : (b - nbu);
    const int* reg = isU ? regu : regi;
    const int* sT  = isU ? sTu : sTi;
    int base_node, nn;
    int *off, *deg, *ent; float* rsd;
    int losh, tsh;
    if (isU) {
        base_node = bidx << SH_U; nn = min(256, nU - base_node);
        off = offu; deg = du; rsd = rsdu; ent = entu;
        losh = 16; tsh = TSH_U;
    } else {
        base_node = bidx << SH_I; nn = min(128, nI - base_node);
        off = offi; deg = di; rsd = rsdi; ent = enti;
        losh = 17; tsh = TSH_I;
    }
    int lomask = (1 << losh) - 1;
    int tid = threadIdx.x;
    if (tid == 0) scursor = 0;
    #pragma unroll
    for (int t = 0; t < T_TILES; ++t) bin_cnt[tid + t * THREADS] = 0;
    __syncthreads();
    // gather this bucket's segment from every chunk region
    for (int c = tid; c < nchunks; c += THREADS) {
        const int* row = sT + (size_t)c * NBMAX;
        int s = row[bidx], e = row[bidx + 1];
        int len = e - s;
        if (len > 0) {
            int base = atomicAdd(&scursor, len);
            const int* src = reg + (size_t)c * BIN_C2 + s;
            for (int j = 0; j < len; ++j) {
                int pos = base + j;
                if (pos < CAP) stash[pos] = src[j];
            }
        }
    }
    __syncthreads();
    int count = min(scursor, CAP);
    // histogram by (node, nbr_tile)
    for (int k = tid; k < count; k += THREADS) {
        int p = stash[k];
        int key = ((p >> losh) << 3) | ((p & lomask) >> tsh);
        atomicAdd(&bin_cnt[key], 1);
    }
    __syncthreads();
    // intra-node exclusive prefix over 8 tile-bins; c = node degree
    int c = 0;
    {
        int base = tid * T_TILES;
        #pragma unroll
        for (int t = 0; t < T_TILES; ++t) {
            int v = bin_cnt[base + t];
            bin_cnt[base + t] = c;
            c += v;
        }
    }
    int seg = (c + 15) & ~15;               // 64B-align per-node segment
    int lane = tid & 63, wid = tid >> 6;
    int inc = seg;
    #pragma unroll
    for (int ofs = 1; ofs < 64; ofs <<= 1) {
        int t = __shfl_up(inc, ofs);
        if (lane >= ofs) inc += t;
    }
    if (lane == 63) wsum[wid] = inc;
    __syncthreads();
    int wofs = 0;
    #pragma unroll
    for (int w = 0; w < 4; ++w) wofs += (w < wid) ? wsum[w] : 0;
    int incl = inc + wofs;
    int excl = incl - seg;
    if (tid == THREADS - 1) bob_sh = atomicAdd(&curs[isU ? 0 : CPAD], incl);
    __syncthreads();
    int bob = bob_sh;
    node_base[tid] = excl;
    if (tid < nn) {
        off[base_node + tid] = bob + excl;
        deg[base_node + tid] = c;
        rsd[base_node + tid] = rsqrtf(fmaxf((float)c, 1.0f));
    }
    __syncthreads();
    #pragma unroll
    for (int t = 0; t < T_TILES; ++t) {
        int k = tid + t * THREADS;
        bin_cnt[k] += node_base[k >> 3];
    }
    __syncthreads();
    for (int k = tid; k < count; k += THREADS) {
        int p = stash[k];
        int key = ((p >> losh) << 3) | ((p & lomask) >> tsh);
        int sl = atomicAdd(&bin_cnt[key], 1);
        ent[bob + sl] = p & lomask;
    }
}

// ---------------- fp32 tables (both) -> fp16 ----------------
__global__ void conv16all(const float* __restrict__ ut, const float* __restrict__ it,
                          __half* __restrict__ dst, int nU16, int ntot16) {
    int stride = gridDim.x * blockDim.x;
    for (int i = blockIdx.x * blockDim.x + threadIdx.x; i < ntot16; i += stride) {
        const float* src = (i < nU16) ? (ut + (size_t)i * 4) : (it + (size_t)(i - nU16) * 4);
        float4 v = *reinterpret_cast<const float4*>(src);
        __half2 h0 = __float22half2_rn(make_float2(v.x, v.y));
        __half2 h1 = __float22half2_rn(make_float2(v.z, v.w));
        uint2 st;
        st.x = *reinterpret_cast<unsigned*>(&h0);
        st.y = *reinterpret_cast<unsigned*>(&h1);
        *reinterpret_cast<uint2*>(dst + (size_t)i * 4) = st;
    }
}

// ---------------- propagation layer (R8 formulation: known-best 62us) ----------------
__global__ void prop16(const __half* __restrict__ x,
                       const int* __restrict__ offu, const int* __restrict__ offi,
                       const int* __restrict__ du, const int* __restrict__ di,
                       const float* __restrict__ rsdu, const float* __restrict__ rsdi,
                       const int* __restrict__ entu, const int* __restrict__ enti,
                       __half* __restrict__ y, int nU, int N) {
    int node = blockIdx.x * (THREADS >> 3) + (threadIdx.x >> 3);
    int lane = threadIdx.x & 7;
    if (node >= N) return;
    const int* ent; const __half* src; const float* rsdn;
    int beg, dg; float rs;
    if (node < nU) {
        beg = offu[node]; dg = du[node]; rs = rsdu[node];
        ent = entu; src = x + ((size_t)nU << 6); rsdn = rsdi;
    } else {
        int i = node - nU;
        beg = offi[i]; dg = di[i]; rs = rsdi[i];
        ent = enti; src = x; rsdn = rsdu;
    }
    float a0=0,a1=0,a2=0,a3=0,a4=0,a5=0,a6=0,a7=0;
    for (int k0 = 0; k0 < dg; k0 += 8) {
        int me = (k0 + lane < dg) ? ent[beg + k0 + lane] : 0;
        #pragma unroll
        for (int j = 0; j < 8; ++j) {
            if (k0 + j < dg) {
                int nbr = __shfl(me, j, 8);
                float w = rsdn[nbr];
                uint4 r = *reinterpret_cast<const uint4*>(src + ((size_t)nbr << 6) + (lane << 3));
                __half2 h0 = *reinterpret_cast<__half2*>(&r.x);
                __half2 h1 = *reinterpret_cast<__half2*>(&r.y);
                __half2 h2 = *reinterpret_cast<__half2*>(&r.z);
                __half2 h3 = *reinterpret_cast<__half2*>(&r.w);
                float2 f0 = __half22float2(h0), f1 = __half22float2(h1);
                float2 f2 = __half22float2(h2), f3 = __half22float2(h3);
                a0 += w * f0.x; a1 += w * f0.y; a2 += w * f1.x; a3 += w * f1.y;
                a4 += w * f2.x; a5 += w * f2.y; a6 += w * f3.x; a7 += w * f3.y;
            }
        }
    }
    __half2 o0 = __float22half2_rn(make_float2(a0 * rs, a1 * rs));
    __half2 o1 = __float22half2_rn(make_float2(a2 * rs, a3 * rs));
    __half2 o2 = __float22half2_rn(make_float2(a4 * rs, a5 * rs));
    __half2 o3 = __float22half2_rn(make_float2(a6 * rs, a7 * rs));
    uint4 st;
    st.x = *reinterpret_cast<unsigned*>(&o0);
    st.y = *reinterpret_cast<unsigned*>(&o1);
    st.z = *reinterpret_cast<unsigned*>(&o2);
    st.w = *reinterpret_cast<unsigned*>(&o3);
    *reinterpret_cast<uint4*>(y + ((size_t)node << 6) + (lane << 3)) = st;
}

// ---------------- fused: sel += x2[row] + rs*sum(rsd[nbr]*x2[nbr]) ----------------
__global__ void prop_sel_acc(const __half* __restrict__ x,
                             const int* __restrict__ users, const int* __restrict__ pos,
                             const int* __restrict__ neg,
                             const int* __restrict__ offu, const int* __restrict__ offi,
                             const int* __restrict__ du, const int* __restrict__ di,
                             const float* __restrict__ rsdu, const float* __restrict__ rsdi,
                             const int* __restrict__ entu, const int* __restrict__ enti,
                             float* __restrict__ sel, int B, int nU) {
    int r = blockIdx.x * (THREADS >> 3) + (threadIdx.x >> 3);
    int lane = threadIdx.x & 7;
    if (r >= 3 * B) return;
    int which = r / B, b = r - which * B;
    const int* ent; const __half* src; const float* rsdn;
    int beg, dg; float rs; size_t selfrow;
    if (which == 0) {
        int u = users[b];
        beg = offu[u]; dg = du[u]; rs = rsdu[u];
        ent = entu; src = x + ((size_t)nU << 6); rsdn = rsdi;
        selfrow = (size_t)u << 6;
    } else {
        int i = (which == 1) ? pos[b] : neg[b];
        beg = offi[i]; dg = di[i]; rs = rsdi[i];
        ent = enti; src = x; rsdn = rsdu;
        selfrow = (size_t)(nU + i) << 6;
    }
    float a0=0,a1=0,a2=0,a3=0,a4=0,a5=0,a6=0,a7=0;
    for (int k0 = 0; k0 < dg; k0 += 8) {
        int me = (k0 + lane < dg) ? ent[beg + k0 + lane] : 0;
        #pragma unroll
        for (int j = 0; j < 8; ++j) {
            if (k0 + j < dg) {
                int nbr = __shfl(me, j, 8);
                float w = rsdn[nbr];
                uint4 rv = *reinterpret_cast<const uint4*>(src + ((size_t)nbr << 6) + (lane << 3));
                __half2 h0 = *reinterpret_cast<__half2*>(&rv.x);
                __half2 h1 = *reinterpret_cast<__half2*>(&rv.y);
                __half2 h2 = *reinterpret_cast<__half2*>(&rv.z);
                __half2 h3 = *reinterpret_cast<__half2*>(&rv.w);
                float2 f0 = __half22float2(h0), f1 = __half22float2(h1);
                float2 f2 = __half22float2(h2), f3 = __half22float2(h3);
                a0 += w * f0.x; a1 += w * f0.y; a2 += w * f1.x; a3 += w * f1.y;
                a4 += w * f2.x; a5 += w * f2.y; a6 += w * f3.x; a7 += w * f3.y;
            }
        }
    }
    uint4 rv = *reinterpret_cast<const uint4*>(x + selfrow + (lane << 3));
    __half2 h0 = *reinterpret_cast<__half2*>(&rv.x);
    __half2 h1 = *reinterpret_cast<__half2*>(&rv.y);
    __half2 h2 = *reinterpret_cast<__half2*>(&rv.z);
    __half2 h3 = *reinterpret_cast<__half2*>(&rv.w);
    float2 s0 = __half22float2(h0), s1 = __half22float2(h1);
    float2 s2 = __half22float2(h2), s3 = __half22float2(h3);
    float* s = sel + ((size_t)r << 6) + (lane << 3);
    float4 d0 = *reinterpret_cast<float4*>(s);
    float4 d1 = *reinterpret_cast<float4*>(s + 4);
    d0.x += s0.x + rs * a0; d0.y += s0.y + rs * a1;
    d0.z += s1.x + rs * a2; d0.w += s1.y + rs * a3;
    d1.x += s2.x + rs * a4; d1.y += s2.y + rs * a5;
    d1.z += s3.x + rs * a6; d1.w += s3.y + rs * a7;
    *reinterpret_cast<float4*>(s) = d0;
    *reinterpret_cast<float4*>(s + 4) = d1;
}

// ---------------- fused: sel = table rows (layer 0) + reg loss ----------------
__global__ void selreg(const float* __restrict__ ut, const float* __restrict__ it,
                       const int* __restrict__ users, const int* __restrict__ pos,
                       const int* __restrict__ neg,
                       float* __restrict__ sel, float* __restrict__ out_reg,
                       int B, float scale) {
    int r = blockIdx.x * (THREADS >> 4) + (threadIdx.x >> 4);
    int t = threadIdx.x & 15;
    float ssq = 0.f;
    if (r < 3 * B) {
        int which = r / B, b = r - which * B;
        const float* base; int idx;
        if (which == 0)      { base = ut; idx = users[b]; }
        else if (which == 1) { base = it; idx = pos[b]; }
        else                 { base = it; idx = neg[b]; }
        float4 v = *reinterpret_cast<const float4*>(base + ((size_t)idx << 6) + t * 4);
        *reinterpret_cast<float4*>(sel + ((size_t)r << 6) + t * 4) = v;
        ssq = v.x * v.x + v.y * v.y + v.z * v.z + v.w * v.w;
    }
    #pragma unroll
    for (int ofs = 32; ofs; ofs >>= 1) ssq += __shfl_down(ssq, ofs);
    if ((threadIdx.x & 63) == 0) atomicAdd(out_reg, ssq * scale);
}

// ---------------- accumulate selected rows from fp16 layer output ----------------
__global__ void sel_acc16(const __half* __restrict__ x,
                          const int* __restrict__ users, const int* __restrict__ pos,
                          const int* __restrict__ neg, float* __restrict__ sel, int B, int nU) {
    int r = blockIdx.x * (THREADS >> 3) + (threadIdx.x >> 3);
    int lane = threadIdx.x & 7;
    if (r >= 3 * B) return;
    int which = r / B, b = r - which * B;
    size_t row;
    if (which == 0)      row = (size_t)users[b];
    else if (which == 1) row = (size_t)nU + pos[b];
    else                 row = (size_t)nU + neg[b];
    uint4 rv = *reinterpret_cast<const uint4*>(x + (row << 6) + (lane << 3));
    __half2 h0 = *reinterpret_cast<__half2*>(&rv.x);
    __half2 h1 = *reinterpret_cast<__half2*>(&rv.y);
    __half2 h2 = *reinterpret_cast<__half2*>(&rv.z);
    __half2 h3 = *reinterpret_cast<__half2*>(&rv.w);
    float2 f0 = __half22float2(h0), f1 = __half22float2(h1);
    float2 f2 = __half22float2(h2), f3 = __half22float2(h3);
    float* s = sel + ((size_t)r << 6) + (lane << 3);
    float4 d0 = *reinterpret_cast<float4*>(s);
    float4 d1 = *reinterpret_cast<float4*>(s + 4);
    d0.x += f0.x; d0.y += f0.y; d0.z += f1.x; d0.w += f1.y;
    d1.x += f2.x; d1.y += f2.y; d1.z += f3.x; d1.w += f3.y;
    *reinterpret_cast<float4*>(s) = d0;
    *reinterpret_cast<float4*>(s + 4) = d1;
}

// ---------------- final scores ----------------
__global__ void score(const float* __restrict__ sel, float* __restrict__ out, int B) {
    int b = blockIdx.x * (THREADS >> 6) + (threadIdx.x >> 6);
    int lane = threadIdx.x & 63;
    if (b >= B) return;
    float u = sel[((size_t)b << 6) + lane];
    float p = sel[((size_t)(B + b) << 6) + lane];
    float n = sel[((size_t)(2 * B + b) << 6) + lane];
    float ps = u * p, ns = u * n;
    for (int ofs = 32; ofs; ofs >>= 1) {
        ps += __shfl_down(ps, ofs);
        ns += __shfl_down(ns, ofs);
    }
    if (lane == 0) {
        out[b]     = ps * (1.0f / 16.0f);
        out[B + b] = ns * (1.0f / 16.0f);
    }
}

extern "C" void kernel_launch(void* const* d_in, const int* in_sizes, int n_in,
                              void* d_out, int out_size, void* d_ws, size_t ws_size,
                              hipStream_t stream) {
    const float* ut   = (const float*)d_in[0];
    const float* it   = (const float*)d_in[1];
    const int* eu     = (const int*)d_in[2];
    const int* ei     = (const int*)d_in[3];
    const int* users  = (const int*)d_in[4];
    const int* pos    = (const int*)d_in[5];
    const int* neg    = (const int*)d_in[6];
    int nU = in_sizes[0] / 64;
    int nI = in_sizes[1] / 64;
    int E  = in_sizes[2];
    int B  = in_sizes[4];
    int N  = nU + nI;
    float* out = (float*)d_out;

    int nbu = (nU + 255) >> SH_U;   // 391
    int nbi = (nI + 127) >> SH_I;   // 391
    int nchunks = (E + BIN_C2 - 1) / BIN_C2;

    char* ws = (char*)d_ws;
    size_t cursor = 0;
    auto alloc = [&](size_t bytes) -> void* {
        cursor = (cursor + 255) & ~(size_t)255;
        void* p = ws + cursor;
        cursor += bytes;
        return p;
    };
    int*   curs = (int*)alloc(2 * CPAD * 4);
    size_t zero_span = cursor;                    // curs zeroed
    int*   regu = (int*)alloc((size_t)nchunks * BIN_C2 * 4);
    int*   regi = (int*)alloc((size_t)nchunks * BIN_C2 * 4);
    int*   sTu  = (int*)alloc((size_t)nchunks * NBMAX * 4);
    int*   sTi  = (int*)alloc((size_t)nchunks * NBMAX * 4);
    int*   offu = (int*)alloc((size_t)nU * 4);
    int*   offi = (int*)alloc((size_t)nI * 4);
    int*   du   = (int*)alloc((size_t)nU * 4);
    int*   di   = (int*)alloc((size_t)nI * 4);
    float* rsdu = (float*)alloc((size_t)nU * 4);
    float* rsdi = (float*)alloc((size_t)nI * 4);
    int*   entu = (int*)alloc(((size_t)E + (size_t)nbu * 256 * 16) * 4);
    int*   enti = (int*)alloc(((size_t)E + (size_t)nbi * 128 * 16) * 4);
    __half* xA  = (__half*)alloc((size_t)N * 64 * 2);
    __half* xB  = (__half*)alloc((size_t)N * 64 * 2);
    float* sel  = (float*)alloc((size_t)3 * B * 64 * 4);

    hipMemsetAsync(d_ws, 0, zero_span, stream);
    hipMemsetAsync(out + 2 * B, 0, sizeof(float), stream);

    // fp16 tables (layer-1 input)
    conv16all<<<2048, THREADS, 0, stream>>>(ut, it, xA, nU * 16, N * 16);

    // graph build: binpack (chunk-private regions) -> place
    binpack<<<dim3(nchunks, 2), THREADS, 0, stream>>>(eu, ei, regu, regi, sTu, sTi, E, nbu, nbi);
    place<<<nbu + nbi, THREADS, 0, stream>>>(regu, regi, sTu, sTi,
                                             offu, offi, du, di, rsdu, rsdi, entu, enti,
                                             curs, nbu, nU, nI, nchunks);

    // layer 0 selected rows + reg loss (fused)
    selreg<<<(3 * B + 15) / 16, THREADS, 0, stream>>>(ut, it, users, pos, neg, sel,
                                                      out + 2 * B, B, 1e-4f / (float)B);

    // layers 1,2 full propagation; layer-2 acc + layer-3 selective fused
    int gridSel16 = (3 * B * 8 + THREADS - 1) / THREADS;
    int gridProp = (N * 8 + THREADS - 1) / THREADS;
    prop16<<<gridProp, THREADS, 0, stream>>>(xA, offu, offi, du, di, rsdu, rsdi, entu, enti, xB, nU, N);
    sel_acc16<<<gridSel16, THREADS, 0, stream>>>(xB, users, pos, neg, sel, B, nU);
    prop16<<<gridProp, THREADS, 0, stream>>>(xB, offu, offi, du, di, rsdu, rsdi, entu, enti, xA, nU, N);
    prop_sel_acc<<<gridSel16, THREADS, 0, stream>>>(xA, users, pos, neg, offu, offi, du, di,
                                                    rsdu, rsdi, entu, enti, sel, B, nU);

    // scores
    score<<<(B + 3) / 4, THREADS, 0, stream>>>(sel, out, B);
}